// Round 10
// baseline (7285.132 us; speedup 1.0000x reference)
//
#include <hip/hip_runtime.h>
#include <hip/hip_bf16.h>
#include <cstddef>

#define BB 32
#define PP 196
#define ENCD 2048
#define EMBD 512
#define DECD 512
#define ATTD 512
#define VV 10000
#define LLEN 52
#define TT 51
#define HPC 8    // k-chunks in k_hproj2 (512/64)
#define GAC 16   // k-chunks in k_gawe2 (2048/128)

// output offsets (floats)
#define OFF_PRED  0
#define OFF_TOKS  16320000
#define OFF_DLEN  16321664
#define OFF_ALPHA 16321696
#define OFF_SIDX  16641568

typedef __attribute__((ext_vector_type(8))) short short8;
typedef __attribute__((ext_vector_type(4))) float floatx4;

__device__ __forceinline__ float sigmf(float x) { return 1.0f / (1.0f + __expf(-x)); }
__device__ __forceinline__ unsigned short f2bf(float x) {
    __hip_bfloat16 h = __float2bfloat16(x);
    return *(unsigned short*)&h;
}

// ---------------------------------------------------------------- sort (+ counter init)
__global__ void k_sort(const int* __restrict__ toks, const int* __restrict__ lens,
                       int* __restrict__ sidx, int* __restrict__ dlen, float* __restrict__ out,
                       unsigned int* __restrict__ cnt) {
    __shared__ int s_idx[BB];
    if (threadIdx.x < 16) cnt[threadIdx.x] = 0u;
    if (threadIdx.x == 0) {
        int idx[BB], ln[BB];
        for (int i = 0; i < BB; i++) { idx[i] = i; ln[i] = lens[i]; }
        for (int i = 1; i < BB; i++) {           // stable insertion sort, descending
            int ci = idx[i], cl = ln[i]; int j = i - 1;
            while (j >= 0 && ln[j] < cl) { ln[j + 1] = ln[j]; idx[j + 1] = idx[j]; j--; }
            ln[j + 1] = cl; idx[j + 1] = ci;
        }
        for (int i = 0; i < BB; i++) {
            s_idx[i] = idx[i];
            sidx[i] = idx[i];
            int d = ln[i] - 1;
            dlen[i] = d;
            out[OFF_DLEN + i] = (float)d;
            out[OFF_SIDX + i] = (float)idx[i];
        }
    }
    __syncthreads();
    for (int i = threadIdx.x; i < BB * LLEN; i += blockDim.x) {
        int b = i / LLEN, l = i % LLEN;
        out[OFF_TOKS + i] = (float)toks[s_idx[b] * LLEN + l];
    }
}

// ---------------------------------------------------------------- mean (parallel, coalesced) -> meanT[e][b]
__global__ void k_mean(const float* __restrict__ img, const int* __restrict__ sidx,
                       float* __restrict__ meanT) {
    int b = blockIdx.x, ec = blockIdx.y, tid = threadIdx.x;
    int e = ec * 256 + tid;
    const float* ib = img + (size_t)sidx[b] * PP * ENCD + e;
    float acc = 0.f;
#pragma unroll 4
    for (int p = 0; p < PP; p++) acc += ib[(size_t)p * ENCD];
    meanT[(size_t)e * BB + b] = acc * (1.0f / 196.0f);
}

// ---------------------------------------------------------------- h0/c0 GEMV: C[col<1024][b] over k=2048
__global__ void k_h0c0(const float* __restrict__ meanT,
                       const float* __restrict__ Wh0, const float* __restrict__ bh0,
                       const float* __restrict__ Wc0, const float* __restrict__ bc0,
                       float* __restrict__ xT, float* __restrict__ c) {
    __shared__ float sx[256 * BB];   // 32 KB
    int tid = threadIdx.x;
    int cl = tid >> 3, bq = tid & 7;              // 32 cols x 8 bq(4 b)
    int col = blockIdx.x * 32 + cl;
    const float* wr = (col < 512) ? Wh0 + (size_t)col * ENCD
                                  : Wc0 + (size_t)(col - 512) * ENCD;
    float acc[4] = {0, 0, 0, 0};
    for (int k0 = 0; k0 < ENCD; k0 += 256) {
        __syncthreads();
        for (int i = tid; i < 256 * BB; i += 256) sx[i] = meanT[(size_t)k0 * BB + i];
        __syncthreads();
        for (int k = 0; k < 256; k++) {
            float w = wr[k0 + k];
            const float* x = sx + k * BB + bq * 4;
            acc[0] += w * x[0]; acc[1] += w * x[1]; acc[2] += w * x[2]; acc[3] += w * x[3];
        }
    }
#pragma unroll
    for (int j = 0; j < 4; j++) {
        int b = bq * 4 + j;
        if (col < 512) {
            float v = acc[j] + bh0[col];
            xT[(size_t)(2048 + col) * BB + b] = v;
        } else {
            float v = acc[j] + bc0[col - 512];
            c[b * DECD + (col - 512)] = v;
        }
    }
}

// ---------------------------------------------------------------- fused h-weight transpose (k-major)
// WhT2[k][col], k<512, col<4608: col<512 -> Wdec[col][k]; col<2560 -> Wbeta[col-512][k];
// else Whh[col-2560][k]  (gate-h part).
__global__ void k_twh2(const float* __restrict__ Wdec, const float* __restrict__ Wbeta,
                       const float* __restrict__ Whh, float* __restrict__ WhT2) {
    __shared__ float sT[32][33];
    int kt = blockIdx.x, ct = blockIdx.y;
    int tx = threadIdx.x & 31, ty = threadIdx.x >> 5;
    for (int j = 0; j < 4; j++) {
        int cc = ct * 32 + ty + j * 8;
        int kk = kt * 32 + tx;
        float v = (cc < 512) ? Wdec[(size_t)cc * 512 + kk]
                 : (cc < 2560) ? Wbeta[(size_t)(cc - 512) * 512 + kk]
                               : Whh[(size_t)(cc - 2560) * 512 + kk];
        sT[ty + j * 8][tx] = v;
    }
    __syncthreads();
    for (int j = 0; j < 4; j++) {
        int kk = kt * 32 + ty + j * 8;
        int cc = ct * 32 + tx;
        WhT2[(size_t)kk * 4608 + cc] = sT[tx][ty + j * 8];
    }
}

// ---------------------------------------------------------------- awe-weight transpose: WgaT[k][d] = Wih[d][512+k]
__global__ void k_twg2(const float* __restrict__ Wih, float* __restrict__ WgaT) {
    __shared__ float sT[32][33];
    int kt = blockIdx.x, dt = blockIdx.y;
    int tx = threadIdx.x & 31, ty = threadIdx.x >> 5;
    for (int j = 0; j < 4; j++) {
        int dd = dt * 32 + ty + j * 8;
        int kk = kt * 32 + tx;
        sT[ty + j * 8][tx] = Wih[(size_t)dd * 2560 + 512 + kk];
    }
    __syncthreads();
    for (int j = 0; j < 4; j++) {
        int kk = kt * 32 + ty + j * 8;
        int dd = dt * 32 + tx;
        WgaT[(size_t)kk * 2048 + dd] = sT[tx][ty + j * 8];
    }
}

// WfcB: bf16 convert of Wfc [10000][512], layout unchanged
__global__ void k_cvtfc(const float* __restrict__ Wfc, unsigned int* __restrict__ WfcB) {
    int base = (blockIdx.x * 256 + threadIdx.x) * 4;
    for (int j = 0; j < 4; j++) {
        int ui = base + j;                 // 0 .. 2,560,000
        const float* src = Wfc + (size_t)ui * 2;
        unsigned int lo = f2bf(src[0]), hi = f2bf(src[1]);
        WfcB[ui] = lo | (hi << 16);
    }
}

// ---------------------------------------------------------------- enc_att = img @ W_enc^T + b_enc
// M=6272, N=512, K=2048. grid (196, 4), block 256. 4x4 register tile, 32x128 block tile,
// K-tile 32. 784 blocks (~3/CU) for latency hiding.
__global__ void k_enc(const float* __restrict__ img, const int* __restrict__ sidx,
                      const float* __restrict__ Wenc, const float* __restrict__ benc,
                      float* __restrict__ enc_att) {
    __shared__ float sA[32][36];     // [k][m], stride 144B (16B aligned)
    __shared__ float sW[32][132];    // [k][n], stride 528B (16B aligned)
    __shared__ size_t sRB[32];
    int mb = blockIdx.x, c0 = blockIdx.y * 128;
    int tid = threadIdx.x;
    int tm = tid >> 5, tn = tid & 31;   // tm 0..7 -> rows tm*4..+4
    if (tid < 32) {
        int row = mb * 32 + tid;
        int b = row / PP, p = row % PP;
        sRB[tid] = ((size_t)sidx[b] * PP + p) * ENCD;
    }
    __syncthreads();
    float acc[4][4];
#pragma unroll
    for (int i = 0; i < 4; i++)
#pragma unroll
        for (int j = 0; j < 4; j++) acc[i][j] = 0.f;

    for (int kk = 0; kk < ENCD; kk += 32) {
        // stage A: 32 m x 32 k (m = tid>>3, kq = tid&7)
        {
            int m = tid >> 3, kq = tid & 7;
            float4 v = *(const float4*)(img + sRB[m] + kk + kq * 4);
            sA[kq * 4 + 0][m] = v.x; sA[kq * 4 + 1][m] = v.y;
            sA[kq * 4 + 2][m] = v.z; sA[kq * 4 + 3][m] = v.w;
        }
        // stage B: 128 n x 32 k (each thread: 16 k of one col)
        {
            int nl = tid & 127, kh = tid >> 7;
            const float* wr = Wenc + (size_t)(c0 + nl) * ENCD + kk + kh * 16;
#pragma unroll
            for (int j = 0; j < 4; j++) {
                float4 v = *(const float4*)(wr + j * 4);
                sW[kh * 16 + j * 4 + 0][nl] = v.x; sW[kh * 16 + j * 4 + 1][nl] = v.y;
                sW[kh * 16 + j * 4 + 2][nl] = v.z; sW[kh * 16 + j * 4 + 3][nl] = v.w;
            }
        }
        __syncthreads();
#pragma unroll
        for (int k = 0; k < 32; k++) {
            float4 a0 = *(const float4*)&sA[k][tm * 4];
            float4 w0 = *(const float4*)&sW[k][tn * 4];
            float av[4] = {a0.x, a0.y, a0.z, a0.w};
            float wv[4] = {w0.x, w0.y, w0.z, w0.w};
#pragma unroll
            for (int i = 0; i < 4; i++)
#pragma unroll
                for (int j = 0; j < 4; j++) acc[i][j] += av[i] * wv[j];
        }
        __syncthreads();
    }
#pragma unroll
    for (int i = 0; i < 4; i++) {
        int row = mb * 32 + tm * 4 + i;
        float* orow = enc_att + (size_t)row * ATTD + c0;
        int ca = tn * 4;
        float4 oa = {acc[i][0] + benc[c0 + ca + 0], acc[i][1] + benc[c0 + ca + 1],
                     acc[i][2] + benc[c0 + ca + 2], acc[i][3] + benc[c0 + ca + 3]};
        *(float4*)(orow + ca) = oa;
    }
}

// ---------------------------------------------------------------- g_base = emb_t @ W_ih[:, :512]^T + b_ih + b_hh
__global__ void k_gemb(const float* __restrict__ emb, const int* __restrict__ toks,
                       const int* __restrict__ sidx, const float* __restrict__ Wih,
                       const float* __restrict__ bih, const float* __restrict__ bhh,
                       float* __restrict__ gbase) {
    __shared__ float As[32][33];
    __shared__ float Ws[32][65];
    __shared__ size_t rb[32];
    int row0 = blockIdx.x * 32, col0 = blockIdx.y * 64;
    int tid = threadIdx.x;
    int tr = tid & 31, tc = tid >> 5;
    if (tid < 32) {
        int t = blockIdx.x, b = tid;
        int tok = toks[sidx[b] * LLEN + t];
        rb[tid] = (size_t)tok * EMBD;
    }
    __syncthreads();
    float acc[8] = {0, 0, 0, 0, 0, 0, 0, 0};
    for (int kk = 0; kk < EMBD; kk += 32) {
        for (int i = tid; i < 1024; i += 256) {
            int r = i >> 5, k = i & 31;
            As[r][k] = emb[rb[r] + kk + k];
        }
        for (int i = tid; i < 2048; i += 256) {
            int cc = i >> 5, k = i & 31;
            Ws[k][cc] = Wih[(size_t)(col0 + cc) * (EMBD + ENCD) + kk + k];
        }
        __syncthreads();
        for (int k = 0; k < 32; k++) {
            float a = As[tr][k];
#pragma unroll
            for (int j = 0; j < 8; j++) acc[j] += a * Ws[k][tc * 8 + j];
        }
        __syncthreads();
    }
    int row = row0 + tr;
    float* crow = gbase + (size_t)row * 2048 + col0 + tc * 8;
#pragma unroll
    for (int j = 0; j < 8; j++) {
        int col = col0 + tc * 8 + j;
        crow[j] = acc[j] + bih[col] + bhh[col];
    }
}

// ---------------------------------------------------------------- per-step: fused h projection (no LDS, 4x2 reg tile)
// hp2[kc][b][col], col<4608. grid (36 colchunk of 128, HPC kc of 64), block 512.
__global__ void k_hproj2(const float* __restrict__ xT, const float* __restrict__ WhT2,
                         float* __restrict__ hp2) {
    int tid = threadIdx.x;
    int cq = tid >> 4, bq = tid & 15;
    int c4 = blockIdx.x * 128 + cq * 4;
    int b2 = bq * 2;
    int k0 = blockIdx.y * 64;
    const float* wp = WhT2 + (size_t)k0 * 4608 + c4;
    const float* xp = xT + (size_t)(2048 + k0) * BB + b2;
    float4 acc0 = make_float4(0.f, 0.f, 0.f, 0.f);
    float4 acc1 = make_float4(0.f, 0.f, 0.f, 0.f);
#pragma unroll 8
    for (int k = 0; k < 64; k++) {
        float4 w = *(const float4*)(wp + (size_t)k * 4608);
        float2 x = *(const float2*)(xp + k * BB);
        acc0.x += x.x * w.x; acc0.y += x.x * w.y; acc0.z += x.x * w.z; acc0.w += x.x * w.w;
        acc1.x += x.y * w.x; acc1.y += x.y * w.y; acc1.z += x.y * w.z; acc1.w += x.y * w.w;
    }
    *(float4*)(hp2 + ((size_t)(blockIdx.y * BB + b2 + 0)) * 4608 + c4) = acc0;
    *(float4*)(hp2 + ((size_t)(blockIdx.y * BB + b2 + 1)) * 4608 + c4) = acc1;
}

// ---------------------------------------------------------------- per-step: raw attention scores
// grid (32 b, 8 p-chunk of 25), block 256. Writes sraw[b*200+p].
__global__ void k_score(const float* __restrict__ hp2, const float* __restrict__ bdec,
                        const float* __restrict__ wfull, const float* __restrict__ enc_att,
                        float* __restrict__ sraw) {
    int b = blockIdx.x, pq = blockIdx.y, tid = threadIdx.x;
    __shared__ float sdec[512], swf[512];
    for (int a = tid; a < 512; a += 256) {
        float v = bdec[a];
#pragma unroll
        for (int kc = 0; kc < HPC; kc++) v += hp2[((size_t)(kc * BB + b)) * 4608 + a];
        sdec[a] = v;
        swf[a] = wfull[a];
    }
    __syncthreads();
    int wv = tid >> 6, ln = tid & 63;
    const float* eb = enc_att + (size_t)b * PP * ATTD;
    const int p0 = pq * 25;
    const int p1 = (p0 + 25 < PP) ? p0 + 25 : PP;
    for (int p = p0 + wv; p < p1; p += 4) {
        const float* er = eb + (size_t)p * ATTD;
        float acc = 0.f;
#pragma unroll
        for (int i = 0; i < 8; i++) {
            int a = ln + i * 64;
            acc += fmaxf(er[a] + sdec[a], 0.f) * swf[a];
        }
#pragma unroll
        for (int off = 32; off; off >>= 1) acc += __shfl_down(acc, off);
        if (ln == 0) sraw[b * 200 + p] = acc;
    }
}

// ---------------------------------------------------------------- per-step: softmax (redundant) + beta gate + awe -> xT
// grid (32 b, 8 ec of 256 e), block 256 = 64 col-quads x 4 p-groups of 49.
__global__ void k_awe2(int t, const float* __restrict__ img, const int* __restrict__ sidx,
                       const float* __restrict__ sraw, const float* __restrict__ hp2,
                       const float* __restrict__ bbeta, const int* __restrict__ dlen,
                       float* __restrict__ xT, float* __restrict__ out_alpha) {
    int b = blockIdx.x, ec = blockIdx.y, tid = threadIdx.x;
    __shared__ float sal[200], sred[256], sgate[256], sp4[1024];
    __shared__ int ssb;
    if (tid == 0) ssb = sidx[b];
    float v = (tid < PP) ? sraw[b * 200 + tid] : -1e30f;
    sred[tid] = v;
    __syncthreads();
    for (int s = 128; s; s >>= 1) { if (tid < s) sred[tid] = fmaxf(sred[tid], sred[tid + s]); __syncthreads(); }
    float mx = sred[0];
    __syncthreads();
    float e = (tid < PP) ? __expf(v - mx) : 0.f;
    sred[tid] = e;
    __syncthreads();
    for (int s = 128; s; s >>= 1) { if (tid < s) sred[tid] += sred[tid + s]; __syncthreads(); }
    float inv = 1.f / sred[0];
    if (tid < PP) sal[tid] = e * inv;
    // beta gate for this 256-e slice (1 per thread)
    {
        int col = 512 + ec * 256 + tid;
        float g = bbeta[ec * 256 + tid];
#pragma unroll
        for (int kc = 0; kc < HPC; kc++) g += hp2[((size_t)(kc * BB + b)) * 4608 + col];
        sgate[tid] = sigmf(g);
    }
    __syncthreads();
    // awe: col = tid&63 (float4 column), pg = tid>>6 (4 p-groups of 49)
    int col4 = tid & 63, pg = tid >> 6;
    const float* ib = img + (size_t)ssb * PP * ENCD + ec * 256 + col4 * 4;
    float4 acc = {0.f, 0.f, 0.f, 0.f};
    const int p0 = pg * 49;
#pragma unroll 7
    for (int p = 0; p < 49; p++) {
        float a = sal[p0 + p];
        float4 vv = *(const float4*)(ib + (size_t)(p0 + p) * ENCD);
        acc.x += a * vv.x; acc.y += a * vv.y; acc.z += a * vv.z; acc.w += a * vv.w;
    }
    *(float4*)(sp4 + tid * 4) = acc;
    __syncthreads();
    if (tid < 64) {
        float4 a0 = *(const float4*)(sp4 + tid * 4);
        float4 a1 = *(const float4*)(sp4 + (64 + tid) * 4);
        float4 a2 = *(const float4*)(sp4 + (128 + tid) * 4);
        float4 a3 = *(const float4*)(sp4 + (192 + tid) * 4);
        int e4 = ec * 256 + tid * 4;
        float r0 = (a0.x + a1.x + a2.x + a3.x) * sgate[tid * 4 + 0];
        float r1 = (a0.y + a1.y + a2.y + a3.y) * sgate[tid * 4 + 1];
        float r2 = (a0.z + a1.z + a2.z + a3.z) * sgate[tid * 4 + 2];
        float r3 = (a0.w + a1.w + a2.w + a3.w) * sgate[tid * 4 + 3];
        xT[(size_t)(e4 + 0) * BB + b] = r0;
        xT[(size_t)(e4 + 1) * BB + b] = r1;
        xT[(size_t)(e4 + 2) * BB + b] = r2;
        xT[(size_t)(e4 + 3) * BB + b] = r3;
    }
    if (ec == 0 && tid < PP) {
        bool act = t < dlen[b];
        out_alpha[((size_t)b * TT + t) * PP + tid] = act ? sal[tid] : 0.f;
    }
}

// ---------------------------------------------------------------- per-step: awe gate GEMM + fused LSTM finish
// grid (16 dg, GAC kc), block 512. Block's 128 cols = 4 gate-slices of 32:
// dcol = g*512 + dg*32 + q8*4  ->  dg owns complete i/f/g/o for d in [dg*32, dg*32+32).
// Last-arriving kc block per dg (device-scope atomic counter) runs the LSTM update.
__global__ void k_gawe2(int t, const float* __restrict__ WgaT, float* __restrict__ gpa,
                        const float* __restrict__ gbase, const float* __restrict__ hp2,
                        const int* __restrict__ dlen, float* __restrict__ xT,
                        float* __restrict__ c, unsigned short* __restrict__ hB,
                        unsigned int* __restrict__ cnt) {
    int tid = threadIdx.x;
    int dg = blockIdx.x, kc = blockIdx.y, k0 = kc * 128;
    int cq = tid >> 4, bq = tid & 15;
    int g = cq >> 3, q8 = cq & 7;
    int dcol = g * 512 + dg * 32 + q8 * 4;
    int b2 = bq * 2;
    const float* wp = WgaT + (size_t)k0 * 2048 + dcol;
    const float* xp = xT + (size_t)k0 * BB + b2;
    float4 acc0 = make_float4(0.f, 0.f, 0.f, 0.f);
    float4 acc1 = make_float4(0.f, 0.f, 0.f, 0.f);
#pragma unroll 8
    for (int k = 0; k < 128; k++) {
        float4 w = *(const float4*)(wp + (size_t)k * 2048);
        float2 x = *(const float2*)(xp + k * BB);
        acc0.x += x.x * w.x; acc0.y += x.x * w.y; acc0.z += x.x * w.z; acc0.w += x.x * w.w;
        acc1.x += x.y * w.x; acc1.y += x.y * w.y; acc1.z += x.y * w.z; acc1.w += x.y * w.w;
    }
    *(float4*)(gpa + ((size_t)(kc * BB + b2 + 0)) * 2048 + dcol) = acc0;
    *(float4*)(gpa + ((size_t)(kc * BB + b2 + 1)) * 2048 + dcol) = acc1;
    // release: make partials device-visible, then count in
    __threadfence();
    __syncthreads();
    __shared__ unsigned int s_old;
    if (tid == 0) s_old = atomicAdd(&cnt[dg], 1u);
    __syncthreads();
    if (s_old != GAC - 1) return;
    // acquire
    __threadfence();
    // finalize: 32 d x 32 b, 512 threads -> 2 outputs each (consecutive tid -> consecutive d)
#pragma unroll
    for (int r = 0; r < 2; r++) {
        int o = tid + r * 512;
        int dl = o & 31, b = o >> 5;
        int dd = dg * 32 + dl;
        bool active = t < dlen[b];
        float gs[4];
#pragma unroll
        for (int q = 0; q < 4; q++) {
            int rr = q * 512 + dd;
            float gv = gbase[((size_t)t * BB + b) * 2048 + rr];
#pragma unroll
            for (int k2 = 0; k2 < HPC; k2++) gv += hp2[((size_t)(k2 * BB + b)) * 4608 + 2560 + rr];
#pragma unroll
            for (int k2 = 0; k2 < GAC; k2++) gv += gpa[((size_t)(k2 * BB + b)) * 2048 + rr];
            gs[q] = gv;
        }
        float i_ = sigmf(gs[0]), f_ = sigmf(gs[1]), g_ = tanhf(gs[2]), o_ = sigmf(gs[3]);
        float cv = c[b * DECD + dd];
        float cn = f_ * cv + i_ * g_;
        float hn = o_ * tanhf(cn);
        float hv;
        if (active) { c[b * DECD + dd] = cn; xT[(size_t)(2048 + dd) * BB + b] = hn; hv = hn; }
        else hv = xT[(size_t)(2048 + dd) * BB + b];
        hB[((size_t)t * BB + b) * DECD + dd] = f2bf(hv);
    }
    if (tid == 0) atomicExch(&cnt[dg], 0u);   // reset for next step
}

// ---------------------------------------------------------------- predictions via bf16 MFMA
__global__ void k_pred(const unsigned short* __restrict__ hB, const unsigned short* __restrict__ WfcB,
                       const float* __restrict__ bfc, const int* __restrict__ dlen,
                       float* __restrict__ out) {
    __shared__ unsigned short sA[32 * 40];
    __shared__ unsigned short sB[256 * 40];
    int t = blockIdx.x, n0 = blockIdx.y * 256;
    int tid = threadIdx.x;
    int wv = tid >> 6, lane = tid & 63;
    int quad = lane >> 4, l16 = lane & 15;

    floatx4 acc[2][4];
#pragma unroll
    for (int i = 0; i < 2; i++)
#pragma unroll
        for (int j = 0; j < 4; j++) acc[i][j] = (floatx4){0.f, 0.f, 0.f, 0.f};

    for (int kk = 0; kk < 512; kk += 32) {
        {
            unsigned int* dst = (unsigned int*)sA;
            for (int j = 0; j < 2; j++) {
                int idx = tid + j * 256;
                int m = idx >> 4, kp = idx & 15;
                dst[m * 20 + kp] = ((const unsigned int*)(hB + ((size_t)(t * 32 + m)) * 512 + kk))[kp];
            }
        }
        {
            unsigned int* dst = (unsigned int*)sB;
#pragma unroll
            for (int j = 0; j < 16; j++) {
                int idx = tid + j * 256;
                int n = idx >> 4, kp = idx & 15;
                int gn = n0 + n;
                unsigned int v = 0u;
                if (gn < VV) v = ((const unsigned int*)(WfcB + (size_t)gn * 512 + kk))[kp];
                dst[n * 20 + kp] = v;
            }
        }
        __syncthreads();
        short8 af[2], bf[4];
#pragma unroll
        for (int mt = 0; mt < 2; mt++)
            af[mt] = *(const short8*)(sA + (mt * 16 + l16) * 40 + quad * 8);
#pragma unroll
        for (int nt = 0; nt < 4; nt++) {
            int nl = wv * 64 + nt * 16 + l16;
            bf[nt] = *(const short8*)(sB + nl * 40 + quad * 8);
        }
#pragma unroll
        for (int mt = 0; mt < 2; mt++)
#pragma unroll
            for (int nt = 0; nt < 4; nt++)
                acc[mt][nt] = __builtin_amdgcn_mfma_f32_16x16x32_bf16(af[mt], bf[nt], acc[mt][nt], 0, 0, 0);
        __syncthreads();
    }
#pragma unroll
    for (int mt = 0; mt < 2; mt++) {
#pragma unroll
        for (int r = 0; r < 4; r++) {
            int m = mt * 16 + quad * 4 + r;
            bool active = t < dlen[m];
            float* orow = out + OFF_PRED + ((size_t)m * TT + t) * VV;
#pragma unroll
            for (int nt = 0; nt < 4; nt++) {
                int n = n0 + wv * 64 + nt * 16 + l16;
                if (n < VV) orow[n] = active ? (acc[mt][nt][r] + bfc[n]) : 0.f;
            }
        }
    }
}

// ---------------------------------------------------------------- launch
extern "C" void kernel_launch(void* const* d_in, const int* in_sizes, int n_in,
                              void* d_out, int out_size, void* d_ws, size_t ws_size,
                              hipStream_t stream) {
    const float* img   = (const float*)d_in[0];
    const int*   toks  = (const int*)d_in[1];
    const int*   lens  = (const int*)d_in[2];
    const float* Wenc  = (const float*)d_in[3];
    const float* benc  = (const float*)d_in[4];
    const float* Wdec  = (const float*)d_in[5];
    const float* bdec  = (const float*)d_in[6];
    const float* wfull = (const float*)d_in[7];
    // d_in[8] = b_full (scalar 0; softmax-invariant)
    const float* emb   = (const float*)d_in[9];
    const float* Wih   = (const float*)d_in[10];
    const float* bih   = (const float*)d_in[11];
    const float* Whh   = (const float*)d_in[12];
    const float* bhh   = (const float*)d_in[13];
    const float* Wh0   = (const float*)d_in[14];
    const float* bh0   = (const float*)d_in[15];
    const float* Wc0   = (const float*)d_in[16];
    const float* bc0   = (const float*)d_in[17];
    const float* Wbeta = (const float*)d_in[18];
    const float* bbeta = (const float*)d_in[19];
    const float* Wfc   = (const float*)d_in[20];
    const float* bfc   = (const float*)d_in[21];
    float* out = (float*)d_out;

    // workspace layout
    char* ws = (char*)d_ws;
    int* sidx = (int*)ws;                  ws += 256;
    int* dlen = (int*)ws;                  ws += 256;
    unsigned int* cnt = (unsigned int*)ws; ws += 256;
    float* c        = (float*)ws;          ws += (size_t)BB * DECD * 4;          // 64 KB
    float* xT       = (float*)ws;          ws += (size_t)2560 * BB * 4;          // 320 KB  [k][b]; tail = hT
    float* meanT    = (float*)ws;          ws += (size_t)ENCD * BB * 4;          // 256 KB
    float* sraw     = (float*)ws;          ws += (size_t)BB * 200 * 4;           // 25 KB
    float* hp2      = (float*)ws;          ws += (size_t)HPC * BB * 4608 * 4;    // 4.7 MB [kc][b][col]
    float* gpa      = (float*)ws;          ws += (size_t)GAC * BB * 2048 * 4;    // 4 MB   [kc][b][d]
    unsigned short* hB = (unsigned short*)ws; ws += (size_t)TT * BB * DECD * 2;  // 1.7 MB
    float* WhT2     = (float*)ws;          ws += (size_t)512 * 4608 * 4;         // 9.4 MB
    float* WgaT     = (float*)ws;          ws += (size_t)2048 * 2048 * 4;        // 16.8 MB
    unsigned int* WfcB = (unsigned int*)ws; ws += (size_t)VV * 512 * 2;          // 10.2 MB
    float* enc_att  = (float*)ws;          ws += (size_t)BB * PP * ATTD * 4;     // 12.8 MB
    float* gbase    = (float*)ws;          ws += (size_t)TT * BB * 2048 * 4;     // 13.4 MB

    k_sort<<<1, 64, 0, stream>>>(toks, lens, sidx, dlen, out, cnt);
    k_mean<<<dim3(32, 8), 256, 0, stream>>>(img, sidx, meanT);
    k_h0c0<<<32, 256, 0, stream>>>(meanT, Wh0, bh0, Wc0, bc0, xT, c);
    k_twh2<<<dim3(16, 144), 256, 0, stream>>>(Wdec, Wbeta, Whh, WhT2);
    k_twg2<<<dim3(64, 64), 256, 0, stream>>>(Wih, WgaT);
    k_cvtfc<<<2500, 256, 0, stream>>>(Wfc, WfcB);
    k_enc<<<dim3(196, 4), 256, 0, stream>>>(img, sidx, Wenc, benc, enc_att);
    k_gemb<<<dim3(51, 32), 256, 0, stream>>>(emb, toks, sidx, Wih, bih, bhh, gbase);

    for (int t = 0; t < TT; t++) {
        k_hproj2<<<dim3(36, HPC), 512, 0, stream>>>(xT, WhT2, hp2);
        k_score<<<dim3(32, 8), 256, 0, stream>>>(hp2, bdec, wfull, enc_att, sraw);
        k_awe2<<<dim3(32, 8), 256, 0, stream>>>(t, img, sidx, sraw, hp2, bbeta, dlen,
                                                xT, out + OFF_ALPHA);
        k_gawe2<<<dim3(16, GAC), 512, 0, stream>>>(t, WgaT, gpa, gbase, hp2, dlen,
                                                   xT, c, hB, cnt);
    }

    k_pred<<<dim3(TT, 40), 256, 0, stream>>>(hB, (const unsigned short*)WfcB, bfc, dlen, out);
}

// Round 11
// 3897.859 us; speedup vs baseline: 1.8690x; 1.8690x over previous
//
#include <hip/hip_runtime.h>
#include <hip/hip_bf16.h>
#include <cstddef>

#define BB 32
#define PP 196
#define ENCD 2048
#define EMBD 512
#define DECD 512
#define ATTD 512
#define VV 10000
#define LLEN 52
#define TT 51
#define HPC 8    // k-chunks in k_hproj2 (512/64)
#define GAC 16   // k-chunks in k_gawe (2048/128)

// output offsets (floats)
#define OFF_PRED  0
#define OFF_TOKS  16320000
#define OFF_DLEN  16321664
#define OFF_ALPHA 16321696
#define OFF_SIDX  16641568

// mega-kernel block ranges (enc first for scheduling priority)
#define MB_ENC   392            // (98 x 4)
#define MB_H0C0  (MB_ENC + 32)
#define MB_GEMB  (MB_H0C0 + 1632)   // (51 x 32)
#define MB_TWH2  (MB_GEMB + 2304)   // (16 x 144)
#define MB_TWG2  (MB_TWH2 + 4096)   // (64 x 64)
#define MB_CVT   (MB_TWG2 + 2500)
#define MB_TOTAL MB_CVT

typedef __attribute__((ext_vector_type(8))) short short8;
typedef __attribute__((ext_vector_type(4))) float floatx4;

__device__ __forceinline__ float sigmf(float x) { return 1.0f / (1.0f + __expf(-x)); }
__device__ __forceinline__ unsigned short f2bf(float x) {
    __hip_bfloat16 h = __float2bfloat16(x);
    return *(unsigned short*)&h;
}

// ---------------------------------------------------------------- sort
__global__ void k_sort(const int* __restrict__ toks, const int* __restrict__ lens,
                       int* __restrict__ sidx, int* __restrict__ dlen, float* __restrict__ out) {
    __shared__ int s_idx[BB];
    if (threadIdx.x == 0) {
        int idx[BB], ln[BB];
        for (int i = 0; i < BB; i++) { idx[i] = i; ln[i] = lens[i]; }
        for (int i = 1; i < BB; i++) {           // stable insertion sort, descending
            int ci = idx[i], cl = ln[i]; int j = i - 1;
            while (j >= 0 && ln[j] < cl) { ln[j + 1] = ln[j]; idx[j + 1] = idx[j]; j--; }
            ln[j + 1] = cl; idx[j + 1] = ci;
        }
        for (int i = 0; i < BB; i++) {
            s_idx[i] = idx[i];
            sidx[i] = idx[i];
            int d = ln[i] - 1;
            dlen[i] = d;
            out[OFF_DLEN + i] = (float)d;
            out[OFF_SIDX + i] = (float)idx[i];
        }
    }
    __syncthreads();
    for (int i = threadIdx.x; i < BB * LLEN; i += blockDim.x) {
        int b = i / LLEN, l = i % LLEN;
        out[OFF_TOKS + i] = (float)toks[s_idx[b] * LLEN + l];
    }
}

// ---------------------------------------------------------------- mean (parallel, coalesced) -> meanT[e][b]
__global__ void k_mean(const float* __restrict__ img, const int* __restrict__ sidx,
                       float* __restrict__ meanT) {
    int b = blockIdx.x, ec = blockIdx.y, tid = threadIdx.x;
    int e = ec * 256 + tid;
    const float* ib = img + (size_t)sidx[b] * PP * ENCD + e;
    float acc = 0.f;
#pragma unroll 4
    for (int p = 0; p < PP; p++) acc += ib[(size_t)p * ENCD];
    meanT[(size_t)e * BB + b] = acc * (1.0f / 196.0f);
}

// ================================================================ mega setup kernel
// One launch; block ranges run the independent setup kernels concurrently.
// Shared memory: 32 KB union buffer.
__global__ void k_mega(const float* __restrict__ img, const int* __restrict__ sidx,
                       const float* __restrict__ Wenc, const float* __restrict__ benc,
                       float* __restrict__ enc_att,
                       const float* __restrict__ meanT,
                       const float* __restrict__ Wh0, const float* __restrict__ bh0,
                       const float* __restrict__ Wc0, const float* __restrict__ bc0,
                       float* __restrict__ xT, float* __restrict__ c,
                       const float* __restrict__ emb, const int* __restrict__ toks,
                       const float* __restrict__ Wih, const float* __restrict__ bih,
                       const float* __restrict__ bhh, float* __restrict__ gbase,
                       const float* __restrict__ Wdec, const float* __restrict__ Wbeta,
                       const float* __restrict__ Whh, float* __restrict__ WhT2,
                       float* __restrict__ WgaT,
                       const float* __restrict__ Wfc, unsigned int* __restrict__ WfcB) {
    __shared__ float S[8192];   // 32 KB union
    int bid = blockIdx.x, tid = threadIdx.x;

    if (bid < MB_ENC) {
        // ---- enc_att = img @ Wenc^T + benc : 64x128 tile, 8x4 reg tile (round-9 k_enc)
        float* sA = S;                     // [16][68]
        float* sW = S + 16 * 68;           // [16][132]
        size_t* sRB = (size_t*)(S + 16 * 68 + 16 * 132);  // [64]
        int mb = bid >> 2, c0 = (bid & 3) * 128;
        int tm = tid >> 5, tn = tid & 31;
        if (tid < 64) {
            int row = mb * 64 + tid;
            int b = row / PP, p = row % PP;
            sRB[tid] = ((size_t)sidx[b] * PP + p) * ENCD;
        }
        __syncthreads();
        float acc[8][4];
#pragma unroll
        for (int i = 0; i < 8; i++)
#pragma unroll
            for (int j = 0; j < 4; j++) acc[i][j] = 0.f;
        for (int kk = 0; kk < ENCD; kk += 16) {
            {
                int m = tid >> 2, kq = tid & 3;
                float4 v = *(const float4*)(img + sRB[m] + kk + kq * 4);
                sA[(kq * 4 + 0) * 68 + m] = v.x; sA[(kq * 4 + 1) * 68 + m] = v.y;
                sA[(kq * 4 + 2) * 68 + m] = v.z; sA[(kq * 4 + 3) * 68 + m] = v.w;
            }
            {
                int nl = tid & 127, kh = tid >> 7;
                const float* wr = Wenc + (size_t)(c0 + nl) * ENCD + kk + kh * 8;
                float4 v0 = *(const float4*)(wr);
                float4 v1 = *(const float4*)(wr + 4);
                sW[(kh * 8 + 0) * 132 + nl] = v0.x; sW[(kh * 8 + 1) * 132 + nl] = v0.y;
                sW[(kh * 8 + 2) * 132 + nl] = v0.z; sW[(kh * 8 + 3) * 132 + nl] = v0.w;
                sW[(kh * 8 + 4) * 132 + nl] = v1.x; sW[(kh * 8 + 5) * 132 + nl] = v1.y;
                sW[(kh * 8 + 6) * 132 + nl] = v1.z; sW[(kh * 8 + 7) * 132 + nl] = v1.w;
            }
            __syncthreads();
#pragma unroll
            for (int k = 0; k < 16; k++) {
                float4 a0 = *(const float4*)&sA[k * 68 + tm * 8];
                float4 a1 = *(const float4*)&sA[k * 68 + tm * 8 + 4];
                float4 w0 = *(const float4*)&sW[k * 132 + tn * 4];
                float av[8] = {a0.x, a0.y, a0.z, a0.w, a1.x, a1.y, a1.z, a1.w};
                float wv[4] = {w0.x, w0.y, w0.z, w0.w};
#pragma unroll
                for (int i = 0; i < 8; i++)
#pragma unroll
                    for (int j = 0; j < 4; j++) acc[i][j] += av[i] * wv[j];
            }
            __syncthreads();
        }
#pragma unroll
        for (int i = 0; i < 8; i++) {
            int row = mb * 64 + tm * 8 + i;
            float* orow = enc_att + (size_t)row * ATTD + c0;
            int ca = tn * 4;
            float4 oa = {acc[i][0] + benc[c0 + ca + 0], acc[i][1] + benc[c0 + ca + 1],
                         acc[i][2] + benc[c0 + ca + 2], acc[i][3] + benc[c0 + ca + 3]};
            *(float4*)(orow + ca) = oa;
        }
    } else if (bid < MB_H0C0) {
        // ---- h0/c0 GEMV over meanT
        float* sx = S;                     // [256*BB] = 32 KB
        int blk = bid - MB_ENC;
        int cl = tid >> 3, bq = tid & 7;
        int col = blk * 32 + cl;
        const float* wr = (col < 512) ? Wh0 + (size_t)col * ENCD
                                      : Wc0 + (size_t)(col - 512) * ENCD;
        float acc[4] = {0, 0, 0, 0};
        for (int k0 = 0; k0 < ENCD; k0 += 256) {
            __syncthreads();
            for (int i = tid; i < 256 * BB; i += 256) sx[i] = meanT[(size_t)k0 * BB + i];
            __syncthreads();
            for (int k = 0; k < 256; k++) {
                float w = wr[k0 + k];
                const float* x = sx + k * BB + bq * 4;
                acc[0] += w * x[0]; acc[1] += w * x[1]; acc[2] += w * x[2]; acc[3] += w * x[3];
            }
        }
#pragma unroll
        for (int j = 0; j < 4; j++) {
            int b = bq * 4 + j;
            if (col < 512) {
                xT[(size_t)(2048 + col) * BB + b] = acc[j] + bh0[col];
            } else {
                c[b * DECD + (col - 512)] = acc[j] + bc0[col - 512];
            }
        }
    } else if (bid < MB_GEMB) {
        // ---- g_base = emb_t @ W_ih[:, :512]^T + b_ih + b_hh
        float* As = S;                      // [32][33]
        float* Ws = S + 32 * 33;            // [32][65]
        size_t* rb = (size_t*)(S + 32 * 33 + 32 * 65);  // [32]
        int blk = bid - MB_H0C0;
        int tblk = blk >> 5, yb = blk & 31;
        int row0 = tblk * 32, col0 = yb * 64;
        int tr = tid & 31, tc = tid >> 5;
        if (tid < 32) {
            int tok = toks[sidx[tid] * LLEN + tblk];
            rb[tid] = (size_t)tok * EMBD;
        }
        __syncthreads();
        float acc[8] = {0, 0, 0, 0, 0, 0, 0, 0};
        for (int kk = 0; kk < EMBD; kk += 32) {
            for (int i = tid; i < 1024; i += 256) {
                int r = i >> 5, k = i & 31;
                As[r * 33 + k] = emb[rb[r] + kk + k];
            }
            for (int i = tid; i < 2048; i += 256) {
                int cc = i >> 5, k = i & 31;
                Ws[k * 65 + cc] = Wih[(size_t)(col0 + cc) * (EMBD + ENCD) + kk + k];
            }
            __syncthreads();
            for (int k = 0; k < 32; k++) {
                float a = As[tr * 33 + k];
#pragma unroll
                for (int j = 0; j < 8; j++) acc[j] += a * Ws[k * 65 + tc * 8 + j];
            }
            __syncthreads();
        }
        int row = row0 + tr;
        float* crow = gbase + (size_t)row * 2048 + col0 + tc * 8;
#pragma unroll
        for (int j = 0; j < 8; j++) {
            int col = col0 + tc * 8 + j;
            crow[j] = acc[j] + bih[col] + bhh[col];
        }
    } else if (bid < MB_TWH2) {
        // ---- WhT2 transpose (Wdec | Wbeta | Whh)
        float* sT = S;                      // [32][33]
        int blk = bid - MB_GEMB;
        int kt = blk & 15, ct = blk >> 4;
        int tx = tid & 31, ty = tid >> 5;
        for (int j = 0; j < 4; j++) {
            int cc = ct * 32 + ty + j * 8;
            int kk = kt * 32 + tx;
            float v = (cc < 512) ? Wdec[(size_t)cc * 512 + kk]
                     : (cc < 2560) ? Wbeta[(size_t)(cc - 512) * 512 + kk]
                                   : Whh[(size_t)(cc - 2560) * 512 + kk];
            sT[(ty + j * 8) * 33 + tx] = v;
        }
        __syncthreads();
        for (int j = 0; j < 4; j++) {
            int kk = kt * 32 + ty + j * 8;
            int cc = ct * 32 + tx;
            WhT2[(size_t)kk * 4608 + cc] = sT[tx * 33 + ty + j * 8];
        }
    } else if (bid < MB_TWG2) {
        // ---- WgaT transpose (awe part of Wih)
        float* sT = S;                      // [32][33]
        int blk = bid - MB_TWH2;
        int kt = blk & 63, dt = blk >> 6;
        int tx = tid & 31, ty = tid >> 5;
        for (int j = 0; j < 4; j++) {
            int dd = dt * 32 + ty + j * 8;
            int kk = kt * 32 + tx;
            sT[(ty + j * 8) * 33 + tx] = Wih[(size_t)dd * 2560 + 512 + kk];
        }
        __syncthreads();
        for (int j = 0; j < 4; j++) {
            int kk = kt * 32 + ty + j * 8;
            int dd = dt * 32 + tx;
            WgaT[(size_t)kk * 2048 + dd] = sT[tx * 33 + ty + j * 8];
        }
    } else {
        // ---- WfcB: bf16 convert of Wfc
        int blk = bid - MB_TWG2;
        int base = (blk * 256 + tid) * 4;
        for (int j = 0; j < 4; j++) {
            int ui = base + j;
            const float* src = Wfc + (size_t)ui * 2;
            unsigned int lo = f2bf(src[0]), hi = f2bf(src[1]);
            WfcB[ui] = lo | (hi << 16);
        }
    }
}

// ---------------------------------------------------------------- per-step: fused h projection (no LDS, 4x2 reg tile)
// hp2[kc][b][col], col<4608. grid (36 colchunk of 128, HPC kc of 64), block 512.
__global__ void k_hproj2(const float* __restrict__ xT, const float* __restrict__ WhT2,
                         float* __restrict__ hp2) {
    int tid = threadIdx.x;
    int cq = tid >> 4, bq = tid & 15;
    int c4 = blockIdx.x * 128 + cq * 4;
    int b2 = bq * 2;
    int k0 = blockIdx.y * 64;
    const float* wp = WhT2 + (size_t)k0 * 4608 + c4;
    const float* xp = xT + (size_t)(2048 + k0) * BB + b2;
    float4 acc0 = make_float4(0.f, 0.f, 0.f, 0.f);
    float4 acc1 = make_float4(0.f, 0.f, 0.f, 0.f);
#pragma unroll 8
    for (int k = 0; k < 64; k++) {
        float4 w = *(const float4*)(wp + (size_t)k * 4608);
        float2 x = *(const float2*)(xp + k * BB);
        acc0.x += x.x * w.x; acc0.y += x.x * w.y; acc0.z += x.x * w.z; acc0.w += x.x * w.w;
        acc1.x += x.y * w.x; acc1.y += x.y * w.y; acc1.z += x.y * w.z; acc1.w += x.y * w.w;
    }
    *(float4*)(hp2 + ((size_t)(blockIdx.y * BB + b2 + 0)) * 4608 + c4) = acc0;
    *(float4*)(hp2 + ((size_t)(blockIdx.y * BB + b2 + 1)) * 4608 + c4) = acc1;
}

// ---------------------------------------------------------------- per-step: raw attention scores
// grid (32 b, 8 p-chunk of 25), block 256. Writes sraw[b*200+p].
__global__ void k_score(const float* __restrict__ hp2, const float* __restrict__ bdec,
                        const float* __restrict__ wfull, const float* __restrict__ enc_att,
                        float* __restrict__ sraw) {
    int b = blockIdx.x, pq = blockIdx.y, tid = threadIdx.x;
    __shared__ float sdec[512], swf[512];
    for (int a = tid; a < 512; a += 256) {
        float v = bdec[a];
#pragma unroll
        for (int kc = 0; kc < HPC; kc++) v += hp2[((size_t)(kc * BB + b)) * 4608 + a];
        sdec[a] = v;
        swf[a] = wfull[a];
    }
    __syncthreads();
    int wv = tid >> 6, ln = tid & 63;
    const float* eb = enc_att + (size_t)b * PP * ATTD;
    const int p0 = pq * 25;
    const int p1 = (p0 + 25 < PP) ? p0 + 25 : PP;
    for (int p = p0 + wv; p < p1; p += 4) {
        const float* er = eb + (size_t)p * ATTD;
        float acc = 0.f;
#pragma unroll
        for (int i = 0; i < 8; i++) {
            int a = ln + i * 64;
            acc += fmaxf(er[a] + sdec[a], 0.f) * swf[a];
        }
#pragma unroll
        for (int off = 32; off; off >>= 1) acc += __shfl_down(acc, off);
        if (ln == 0) sraw[b * 200 + p] = acc;
    }
}

// ---------------------------------------------------------------- per-step: softmax (redundant) + beta gate + awe -> xT
// grid (32 b, 8 ec of 256 e), block 256 = 64 col-quads x 4 p-groups of 49.
__global__ void k_awe2(int t, const float* __restrict__ img, const int* __restrict__ sidx,
                       const float* __restrict__ sraw, const float* __restrict__ hp2,
                       const float* __restrict__ bbeta, const int* __restrict__ dlen,
                       float* __restrict__ xT, float* __restrict__ out_alpha) {
    int b = blockIdx.x, ec = blockIdx.y, tid = threadIdx.x;
    __shared__ float sal[200], sred[256], sgate[256], sp4[1024];
    __shared__ int ssb;
    if (tid == 0) ssb = sidx[b];
    float v = (tid < PP) ? sraw[b * 200 + tid] : -1e30f;
    sred[tid] = v;
    __syncthreads();
    for (int s = 128; s; s >>= 1) { if (tid < s) sred[tid] = fmaxf(sred[tid], sred[tid + s]); __syncthreads(); }
    float mx = sred[0];
    __syncthreads();
    float e = (tid < PP) ? __expf(v - mx) : 0.f;
    sred[tid] = e;
    __syncthreads();
    for (int s = 128; s; s >>= 1) { if (tid < s) sred[tid] += sred[tid + s]; __syncthreads(); }
    float inv = 1.f / sred[0];
    if (tid < PP) sal[tid] = e * inv;
    // beta gate for this 256-e slice (1 per thread)
    {
        int col = 512 + ec * 256 + tid;
        float g = bbeta[ec * 256 + tid];
#pragma unroll
        for (int kc = 0; kc < HPC; kc++) g += hp2[((size_t)(kc * BB + b)) * 4608 + col];
        sgate[tid] = sigmf(g);
    }
    __syncthreads();
    // awe: col = tid&63 (float4 column), pg = tid>>6 (4 p-groups of 49)
    int col4 = tid & 63, pg = tid >> 6;
    const float* ib = img + (size_t)ssb * PP * ENCD + ec * 256 + col4 * 4;
    float4 acc = {0.f, 0.f, 0.f, 0.f};
    const int p0 = pg * 49;
#pragma unroll 7
    for (int p = 0; p < 49; p++) {
        float a = sal[p0 + p];
        float4 vv = *(const float4*)(ib + (size_t)(p0 + p) * ENCD);
        acc.x += a * vv.x; acc.y += a * vv.y; acc.z += a * vv.z; acc.w += a * vv.w;
    }
    *(float4*)(sp4 + tid * 4) = acc;
    __syncthreads();
    if (tid < 64) {
        float4 a0 = *(const float4*)(sp4 + tid * 4);
        float4 a1 = *(const float4*)(sp4 + (64 + tid) * 4);
        float4 a2 = *(const float4*)(sp4 + (128 + tid) * 4);
        float4 a3 = *(const float4*)(sp4 + (192 + tid) * 4);
        int e4 = ec * 256 + tid * 4;
        float r0 = (a0.x + a1.x + a2.x + a3.x) * sgate[tid * 4 + 0];
        float r1 = (a0.y + a1.y + a2.y + a3.y) * sgate[tid * 4 + 1];
        float r2 = (a0.z + a1.z + a2.z + a3.z) * sgate[tid * 4 + 2];
        float r3 = (a0.w + a1.w + a2.w + a3.w) * sgate[tid * 4 + 3];
        xT[(size_t)(e4 + 0) * BB + b] = r0;
        xT[(size_t)(e4 + 1) * BB + b] = r1;
        xT[(size_t)(e4 + 2) * BB + b] = r2;
        xT[(size_t)(e4 + 3) * BB + b] = r3;
    }
    if (ec == 0 && tid < PP) {
        bool act = t < dlen[b];
        out_alpha[((size_t)b * TT + t) * PP + tid] = act ? sal[tid] : 0.f;
    }
}

// ---------------------------------------------------------------- per-step: awe-part gate GEMM (no LDS, 4x2 reg tile)
// gpa[kc][b][d]. grid (16 dchunk of 128, GAC kc of 128), block 512 = 32 d-quads x 16 b-pairs.
__global__ void k_gawe(const float* __restrict__ xT, const float* __restrict__ WgaT,
                       float* __restrict__ gpa) {
    int tid = threadIdx.x;
    int dq = tid >> 4, bq = tid & 15;
    int d4 = blockIdx.x * 128 + dq * 4;
    int b2 = bq * 2;
    int k0 = blockIdx.y * 128;
    const float* wp = WgaT + (size_t)k0 * 2048 + d4;
    const float* xp = xT + (size_t)k0 * BB + b2;
    float4 acc0 = make_float4(0.f, 0.f, 0.f, 0.f);
    float4 acc1 = make_float4(0.f, 0.f, 0.f, 0.f);
#pragma unroll 8
    for (int k = 0; k < 128; k++) {
        float4 w = *(const float4*)(wp + (size_t)k * 2048);
        float2 x = *(const float2*)(xp + k * BB);
        acc0.x += x.x * w.x; acc0.y += x.x * w.y; acc0.z += x.x * w.z; acc0.w += x.x * w.w;
        acc1.x += x.y * w.x; acc1.y += x.y * w.y; acc1.z += x.y * w.z; acc1.w += x.y * w.w;
    }
    *(float4*)(gpa + ((size_t)(blockIdx.y * BB + b2 + 0)) * 2048 + d4) = acc0;
    *(float4*)(gpa + ((size_t)(blockIdx.y * BB + b2 + 1)) * 2048 + d4) = acc1;
}

// ---------------------------------------------------------------- per-step: LSTM cell update
// grid 256 blocks x 64 threads: b = blk>>3, d-octant = blk&7.
__global__ void k_update2(int t, const float* __restrict__ gbase, const float* __restrict__ hp2,
                          const float* __restrict__ gpa, const int* __restrict__ dlen,
                          float* __restrict__ xT, float* __restrict__ c,
                          unsigned short* __restrict__ hB) {
    int b = blockIdx.x >> 3;
    int d = (blockIdx.x & 7) * 64 + threadIdx.x;
    bool active = t < dlen[b];
    const float* gb = gbase + ((size_t)t * BB + b) * 2048;
    float gs[4];
#pragma unroll
    for (int q = 0; q < 4; q++) {
        int r = d + q * 512;
        float g = gb[r];
#pragma unroll
        for (int kc = 0; kc < HPC; kc++) g += hp2[((size_t)(kc * BB + b)) * 4608 + 2560 + r];
#pragma unroll
        for (int kc = 0; kc < GAC; kc++) g += gpa[((size_t)(kc * BB + b)) * 2048 + r];
        gs[q] = g;
    }
    float i_ = sigmf(gs[0]), f_ = sigmf(gs[1]), g_ = tanhf(gs[2]), o_ = sigmf(gs[3]);
    float cv = c[b * DECD + d];
    float cn = f_ * cv + i_ * g_;
    float hn = o_ * tanhf(cn);
    float hv;
    if (active) { c[b * DECD + d] = cn; xT[(size_t)(2048 + d) * BB + b] = hn; hv = hn; }
    else hv = xT[(size_t)(2048 + d) * BB + b];
    hB[((size_t)t * BB + b) * DECD + d] = f2bf(hv);
}

// ---------------------------------------------------------------- predictions via bf16 MFMA
__global__ void k_pred(const unsigned short* __restrict__ hB, const unsigned short* __restrict__ WfcB,
                       const float* __restrict__ bfc, const int* __restrict__ dlen,
                       float* __restrict__ out) {
    __shared__ unsigned short sA[32 * 40];
    __shared__ unsigned short sB[256 * 40];
    int t = blockIdx.x, n0 = blockIdx.y * 256;
    int tid = threadIdx.x;
    int wv = tid >> 6, lane = tid & 63;
    int quad = lane >> 4, l16 = lane & 15;

    floatx4 acc[2][4];
#pragma unroll
    for (int i = 0; i < 2; i++)
#pragma unroll
        for (int j = 0; j < 4; j++) acc[i][j] = (floatx4){0.f, 0.f, 0.f, 0.f};

    for (int kk = 0; kk < 512; kk += 32) {
        {
            unsigned int* dst = (unsigned int*)sA;
            for (int j = 0; j < 2; j++) {
                int idx = tid + j * 256;
                int m = idx >> 4, kp = idx & 15;
                dst[m * 20 + kp] = ((const unsigned int*)(hB + ((size_t)(t * 32 + m)) * 512 + kk))[kp];
            }
        }
        {
            unsigned int* dst = (unsigned int*)sB;
#pragma unroll
            for (int j = 0; j < 16; j++) {
                int idx = tid + j * 256;
                int n = idx >> 4, kp = idx & 15;
                int gn = n0 + n;
                unsigned int v = 0u;
                if (gn < VV) v = ((const unsigned int*)(WfcB + (size_t)gn * 512 + kk))[kp];
                dst[n * 20 + kp] = v;
            }
        }
        __syncthreads();
        short8 af[2], bf[4];
#pragma unroll
        for (int mt = 0; mt < 2; mt++)
            af[mt] = *(const short8*)(sA + (mt * 16 + l16) * 40 + quad * 8);
#pragma unroll
        for (int nt = 0; nt < 4; nt++) {
            int nl = wv * 64 + nt * 16 + l16;
            bf[nt] = *(const short8*)(sB + nl * 40 + quad * 8);
        }
#pragma unroll
        for (int mt = 0; mt < 2; mt++)
#pragma unroll
            for (int nt = 0; nt < 4; nt++)
                acc[mt][nt] = __builtin_amdgcn_mfma_f32_16x16x32_bf16(af[mt], bf[nt], acc[mt][nt], 0, 0, 0);
        __syncthreads();
    }
#pragma unroll
    for (int mt = 0; mt < 2; mt++) {
#pragma unroll
        for (int r = 0; r < 4; r++) {
            int m = mt * 16 + quad * 4 + r;
            bool active = t < dlen[m];
            float* orow = out + OFF_PRED + ((size_t)m * TT + t) * VV;
#pragma unroll
            for (int nt = 0; nt < 4; nt++) {
                int n = n0 + wv * 64 + nt * 16 + l16;
                if (n < VV) orow[n] = active ? (acc[mt][nt][r] + bfc[n]) : 0.f;
            }
        }
    }
}

// ---------------------------------------------------------------- launch
extern "C" void kernel_launch(void* const* d_in, const int* in_sizes, int n_in,
                              void* d_out, int out_size, void* d_ws, size_t ws_size,
                              hipStream_t stream) {
    const float* img   = (const float*)d_in[0];
    const int*   toks  = (const int*)d_in[1];
    const int*   lens  = (const int*)d_in[2];
    const float* Wenc  = (const float*)d_in[3];
    const float* benc  = (const float*)d_in[4];
    const float* Wdec  = (const float*)d_in[5];
    const float* bdec  = (const float*)d_in[6];
    const float* wfull = (const float*)d_in[7];
    // d_in[8] = b_full (scalar 0; softmax-invariant)
    const float* emb   = (const float*)d_in[9];
    const float* Wih   = (const float*)d_in[10];
    const float* bih   = (const float*)d_in[11];
    const float* Whh   = (const float*)d_in[12];
    const float* bhh   = (const float*)d_in[13];
    const float* Wh0   = (const float*)d_in[14];
    const float* bh0   = (const float*)d_in[15];
    const float* Wc0   = (const float*)d_in[16];
    const float* bc0   = (const float*)d_in[17];
    const float* Wbeta = (const float*)d_in[18];
    const float* bbeta = (const float*)d_in[19];
    const float* Wfc   = (const float*)d_in[20];
    const float* bfc   = (const float*)d_in[21];
    float* out = (float*)d_out;

    // workspace layout
    char* ws = (char*)d_ws;
    int* sidx = (int*)ws;                  ws += 256;
    int* dlen = (int*)ws;                  ws += 256;
    float* c        = (float*)ws;          ws += (size_t)BB * DECD * 4;          // 64 KB
    float* xT       = (float*)ws;          ws += (size_t)2560 * BB * 4;          // 320 KB  [k][b]; tail = hT
    float* meanT    = (float*)ws;          ws += (size_t)ENCD * BB * 4;          // 256 KB
    float* sraw     = (float*)ws;          ws += (size_t)BB * 200 * 4;           // 25 KB
    float* hp2      = (float*)ws;          ws += (size_t)HPC * BB * 4608 * 4;    // 4.7 MB [kc][b][col]
    float* gpa      = (float*)ws;          ws += (size_t)GAC * BB * 2048 * 4;    // 4 MB   [kc][b][d]
    unsigned short* hB = (unsigned short*)ws; ws += (size_t)TT * BB * DECD * 2;  // 1.7 MB
    float* WhT2     = (float*)ws;          ws += (size_t)512 * 4608 * 4;         // 9.4 MB
    float* WgaT     = (float*)ws;          ws += (size_t)2048 * 2048 * 4;        // 16.8 MB
    unsigned int* WfcB = (unsigned int*)ws; ws += (size_t)VV * 512 * 2;          // 10.2 MB
    float* enc_att  = (float*)ws;          ws += (size_t)BB * PP * ATTD * 4;     // 12.8 MB
    float* gbase    = (float*)ws;          ws += (size_t)TT * BB * 2048 * 4;     // 13.4 MB

    k_sort<<<1, 64, 0, stream>>>(toks, lens, sidx, dlen, out);
    k_mean<<<dim3(32, 8), 256, 0, stream>>>(img, sidx, meanT);
    k_mega<<<MB_TOTAL, 256, 0, stream>>>(img, sidx, Wenc, benc, enc_att,
                                         meanT, Wh0, bh0, Wc0, bc0, xT, c,
                                         emb, toks, Wih, bih, bhh, gbase,
                                         Wdec, Wbeta, Whh, WhT2, WgaT,
                                         Wfc, WfcB);

    for (int t = 0; t < TT; t++) {
        k_hproj2<<<dim3(36, HPC), 512, 0, stream>>>(xT, WhT2, hp2);
        k_score<<<dim3(32, 8), 256, 0, stream>>>(hp2, bdec, wfull, enc_att, sraw);
        k_awe2<<<dim3(32, 8), 256, 0, stream>>>(t, img, sidx, sraw, hp2, bbeta, dlen,
                                                xT, out + OFF_ALPHA);
        k_gawe<<<dim3(16, GAC), 512, 0, stream>>>(xT, WgaT, gpa);
        k_update2<<<256, 64, 0, stream>>>(t, gbase, hp2, gpa, dlen, xT, c, hB);
    }

    k_pred<<<dim3(TT, 40), 256, 0, stream>>>(hB, (const unsigned short*)WfcB, bfc, dlen, out);
}